// Round 2
// baseline (245.748 us; speedup 1.0000x reference)
//
#include <hip/hip_runtime.h>

#define NFULL 128
#define NOUT  122

// LDS strides (in floats)
#define S1_R 34            // 32 cols + 2 pad (even, keeps float2 align; bank shift 2/row)
#define S1_Q 748           // 22 * 34
#define S2_R 34
#define S2_Q 546           // 16 * 34 + 2 (avoid mod-32==0 q-stride)
#define NBLK 1536

__device__ __forceinline__ void phaseA_task(const float* __restrict__ px,
                                            const float* __restrict__ py,
                                            float* __restrict__ s1p)
{
    float xs[8], ys[8];
#pragma unroll
    for (int k = 0; k < 4; ++k) {
        float2 tx = *(const float2*)(px + 2 * k);
        float2 ty = *(const float2*)(py + 2 * k);
        xs[2 * k] = tx.x; xs[2 * k + 1] = tx.y;
        ys[2 * k] = ty.x; ys[2 * k + 1] = ty.y;
    }
    float sx = 0.f, sy = 0.f, sxx = 0.f, syy = 0.f, sxy = 0.f;
#pragma unroll
    for (int k = 0; k < 7; ++k) {
        sx += xs[k]; sy += ys[k];
        sxx = fmaf(xs[k], xs[k], sxx);
        syy = fmaf(ys[k], ys[k], syy);
        sxy = fmaf(xs[k], ys[k], sxy);
    }
    float tx2 = sx - xs[0] + xs[7];
    float ty2 = sy - ys[0] + ys[7];
    float txx = sxx - xs[0] * xs[0] + xs[7] * xs[7];
    float tyy = syy - ys[0] * ys[0] + ys[7] * ys[7];
    float txy = sxy - xs[0] * ys[0] + xs[7] * ys[7];
    *(float2*)(s1p + 0 * S1_Q) = make_float2(sx,  tx2);
    *(float2*)(s1p + 1 * S1_Q) = make_float2(sy,  ty2);
    *(float2*)(s1p + 2 * S1_Q) = make_float2(sxx, txx);
    *(float2*)(s1p + 3 * S1_Q) = make_float2(syy, tyy);
    *(float2*)(s1p + 4 * S1_Q) = make_float2(sxy, txy);
}

__global__ __launch_bounds__(256, 6)
void ssim3d_kernel(const float* __restrict__ X, const float* __restrict__ Y,
                   const float* __restrict__ DR, double* __restrict__ ws, int mode)
{
    __shared__ __align__(16) float s1[5 * S1_Q];   // 14960 B
    __shared__ __align__(16) float s2[5 * S2_Q];   // 10920 B

    const int tid = threadIdx.x;
    int bi = blockIdx.x;
    const int bb = bi & 3;  bi >>= 2;   // batch
    const int ht = bi & 7;  bi >>= 3;   // 8 h-tiles of 16
    const int wt = bi & 3;  bi >>= 2;   // 4 w-tiles (0:0-31,1:32-63,2:64-89,3:90-121)
    const int dc = bi;                  // 12 d-chunks

    const int h0 = ht << 4;
    const int w0 = (wt == 3) ? 90 : (wt << 5);
    const int w_hi = (wt == 3) ? 122 : ((wt == 2) ? 90 : (w0 + 32));
    const int csize = 10 + (dc < 2 ? 1 : 0);
    const int d0 = dc * 10 + (dc < 2 ? dc : 2);
    const int nsl = csize + 6;          // input slices: d0 .. d0+nsl-1 (<=127 always)

    const float dr = DR[bb];
    const float c1 = (0.01f * dr) * (0.01f * dr);
    const float c2 = (0.03f * dr) * (0.03f * dr);
    const float inv_n = 1.0f / 343.0f;
    const float covn = 343.0f / 342.0f;

    // phase A mapping: task t -> row = t>>4 (0..21), colpair sA = t&15
    const int sA  = tid & 15;
    const int rA0 = tid >> 4;           // rows 0..15 (all 256 threads)
    const int rA1 = 16 + (tid >> 4);    // rows 16..21 (tid < 96)
    int grA0 = h0 + rA0; if (grA0 > NFULL - 1) grA0 = NFULL - 1;
    int grA1 = h0 + rA1; if (grA1 > NFULL - 1) grA1 = NFULL - 1;
    const int coffA = w0 + 2 * sA;

    // phase B mapping: 320 tasks: sC=t&15, q=(t>>4)%5, seg=(t>>4)/5
    // phase C mapping:
    const int sC = tid & 15, hC = tid >> 4;
    const int gh  = h0 + hC;
    const int gw0 = w0 + 2 * sC;
    const bool vh = (gh < NOUT);
    const bool vld0 = vh && (gw0 < w_hi);
    const bool vld1 = vh && (gw0 + 1 < w_hi);

    const size_t planeStride = (size_t)NFULL * NFULL;
    const size_t bbase = (size_t)bb * NFULL * planeStride;

    float2 ring[7][5];
    float2 run[5];
#pragma unroll
    for (int k = 0; k < 7; ++k)
#pragma unroll
        for (int q = 0; q < 5; ++q) ring[k][q] = make_float2(0.f, 0.f);
#pragma unroll
    for (int q = 0; q < 5; ++q) run[q] = make_float2(0.f, 0.f);
    float acc = 0.0f;

    for (int base = 0; base <= nsl; base += 7) {
#pragma unroll
        for (int u = 0; u < 7; ++u) {
            const int s = base + u;     // uniform
            if (s <= nsl) {
                // ---------- phase 1: A(s) (global -> s1) || C(s-1) (s2 -> ring/SSIM)
                if (s < nsl) {
                    const int dIn = d0 + s;
                    const float* Xp = X + bbase + (size_t)dIn * planeStride;
                    const float* Yp = Y + bbase + (size_t)dIn * planeStride;
                    phaseA_task(Xp + grA0 * NFULL + coffA, Yp + grA0 * NFULL + coffA,
                                s1 + rA0 * S1_R + 2 * sA);
                    if (tid < 96)
                        phaseA_task(Xp + grA1 * NFULL + coffA, Yp + grA1 * NFULL + coffA,
                                    s1 + rA1 * S1_R + 2 * sA);
                }
                if (s >= 1) {
                    const int slot = (u + 6) % 7;   // (s-1)%7, static after unroll
                    float2 p[5];
#pragma unroll
                    for (int q = 0; q < 5; ++q)
                        p[q] = *(const float2*)(s2 + q * S2_Q + hC * S2_R + 2 * sC);
#pragma unroll
                    for (int q = 0; q < 5; ++q) {
                        run[q].x += p[q].x - ring[slot][q].x;
                        run[q].y += p[q].y - ring[slot][q].y;
                        ring[slot][q] = p[q];
                    }
                    if (s >= 7) {
#pragma unroll
                        for (int j = 0; j < 2; ++j) {
                            const bool vld = j ? vld1 : vld0;
                            if (vld) {
                                float ux  = (j ? run[0].y : run[0].x) * inv_n;
                                float uy  = (j ? run[1].y : run[1].x) * inv_n;
                                float uxx = (j ? run[2].y : run[2].x) * inv_n;
                                float uyy = (j ? run[3].y : run[3].x) * inv_n;
                                float uxy = (j ? run[4].y : run[4].x) * inv_n;
                                float vx  = covn * (uxx - ux * ux);
                                float vy  = covn * (uyy - uy * uy);
                                float vxy = covn * (uxy - ux * uy);
                                float A1  = 2.f * ux * uy + c1;
                                float A2  = 2.f * vxy + c2;
                                float B1v = ux * ux + uy * uy + c1;
                                float B2v = vx + vy + c2;
                                acc += (A1 * A2) / (B1v * B2v);
                            }
                        }
                    }
                }
                __syncthreads();
                // ---------- phase 2: B(s) (s1 -> s2), 320 4-row rolling tasks
                if (s < nsl) {
#pragma unroll
                    for (int rep = 0; rep < 2; ++rep) {
                        const int t = rep ? (256 + tid) : tid;
                        if (rep == 0 || tid < 64) {
                            const int sB  = t & 15;
                            const int tq  = t >> 4;
                            const int qB  = tq % 5;
                            const int seg = tq / 5;       // 0..3
                            const int r0  = seg << 2;
                            const float* src = s1 + qB * S1_Q + 2 * sB;
                            float*       dst = s2 + qB * S2_Q + 2 * sB;
                            float2 v[10];
#pragma unroll
                            for (int r = 0; r < 10; ++r)
                                v[r] = *(const float2*)(src + (r0 + r) * S1_R);
                            float ax = v[0].x, ay = v[0].y;
#pragma unroll
                            for (int r = 1; r < 7; ++r) { ax += v[r].x; ay += v[r].y; }
                            *(float2*)(dst + r0 * S2_R) = make_float2(ax, ay);
#pragma unroll
                            for (int i = 1; i < 4; ++i) {
                                ax += v[6 + i].x - v[i - 1].x;
                                ay += v[6 + i].y - v[i - 1].y;
                                *(float2*)(dst + (r0 + i) * S2_R) = make_float2(ax, ay);
                            }
                        }
                    }
                }
                __syncthreads();
            }
        }
    }

    // ---- reduction: wave shuffle -> LDS -> per-block partial (double) ----
#pragma unroll
    for (int off = 32; off; off >>= 1) acc += __shfl_down(acc, off);
    if ((tid & 63) == 0) s1[tid >> 6] = acc;
    __syncthreads();
    if (tid == 0) {
        double t = (double)s1[0] + (double)s1[1] + (double)s1[2] + (double)s1[3];
        if (mode) ws[blockIdx.x] = t;
        else      atomicAdd(ws, t);
    }
}

__global__ void ssim3d_finalize(const double* __restrict__ ws, float* __restrict__ out, int mode)
{
    if (mode) {
        __shared__ double sm[4];
        const int tid = threadIdx.x;
        double t = 0.0;
        for (int i = tid; i < NBLK; i += 256) t += ws[i];
#pragma unroll
        for (int off = 32; off; off >>= 1) t += __shfl_down(t, off);
        if ((tid & 63) == 0) sm[tid >> 6] = t;
        __syncthreads();
        if (tid == 0) {
            double r = sm[0] + sm[1] + sm[2] + sm[3];
            out[0] = (float)(r * (1.0 / 7263392.0));   // 4 * 122^3
        }
    } else {
        if (threadIdx.x == 0)
            out[0] = (float)(ws[0] * (1.0 / 7263392.0));
    }
}

extern "C" void kernel_launch(void* const* d_in, const int* in_sizes, int n_in,
                              void* d_out, int out_size, void* d_ws, size_t ws_size,
                              hipStream_t stream)
{
    const float* X  = (const float*)d_in[0];
    const float* Y  = (const float*)d_in[1];
    const float* DR = (const float*)d_in[2];
    double* ws = (double*)d_ws;

    const int mode = (ws_size >= NBLK * sizeof(double)) ? 1 : 0;
    if (!mode) hipMemsetAsync(d_ws, 0, sizeof(double), stream);
    ssim3d_kernel<<<NBLK, 256, 0, stream>>>(X, Y, DR, ws, mode);
    ssim3d_finalize<<<1, 256, 0, stream>>>(ws, (float*)d_out, mode);
}

// Round 3
// 143.891 us; speedup vs baseline: 1.7079x; 1.7079x over previous
//
#include <hip/hip_runtime.h>

#define NFULL 128
#define NOUT  122

// LDS strides (in floats)
#define S1_R 34            // 32 cols + 2 pad
#define S1_Q 748           // 22 * 34
#define S2_R 34
#define S2_Q 546           // 16 * 34 + 2
#define NBLK 1024

__device__ __forceinline__ void phaseA_task(const float* __restrict__ px,
                                            const float* __restrict__ py,
                                            float* __restrict__ s1p)
{
    float xs[8], ys[8];
#pragma unroll
    for (int k = 0; k < 4; ++k) {
        float2 tx = *(const float2*)(px + 2 * k);
        float2 ty = *(const float2*)(py + 2 * k);
        xs[2 * k] = tx.x; xs[2 * k + 1] = tx.y;
        ys[2 * k] = ty.x; ys[2 * k + 1] = ty.y;
    }
    float sx = 0.f, sy = 0.f, sxx = 0.f, syy = 0.f, sxy = 0.f;
#pragma unroll
    for (int k = 0; k < 7; ++k) {
        sx += xs[k]; sy += ys[k];
        sxx = fmaf(xs[k], xs[k], sxx);
        syy = fmaf(ys[k], ys[k], syy);
        sxy = fmaf(xs[k], ys[k], sxy);
    }
    float tx2 = sx - xs[0] + xs[7];
    float ty2 = sy - ys[0] + ys[7];
    float txx = sxx - xs[0] * xs[0] + xs[7] * xs[7];
    float tyy = syy - ys[0] * ys[0] + ys[7] * ys[7];
    float txy = sxy - xs[0] * ys[0] + xs[7] * ys[7];
    *(float2*)(s1p + 0 * S1_Q) = make_float2(sx,  tx2);
    *(float2*)(s1p + 1 * S1_Q) = make_float2(sy,  ty2);
    *(float2*)(s1p + 2 * S1_Q) = make_float2(sxx, txx);
    *(float2*)(s1p + 3 * S1_Q) = make_float2(syy, tyy);
    *(float2*)(s1p + 4 * S1_Q) = make_float2(sxy, txy);
}

__global__ __launch_bounds__(256, 4)
void ssim3d_kernel(const float* __restrict__ X, const float* __restrict__ Y,
                   const float* __restrict__ DR, double* __restrict__ ws, int mode)
{
    __shared__ __align__(16) float s1[5 * S1_Q];   // 14960 B
    __shared__ __align__(16) float s2[5 * S2_Q];   // 10920 B

    const int tid = threadIdx.x;
    int bi = blockIdx.x;
    const int bb = bi & 3;  bi >>= 2;   // batch
    const int ht = bi & 7;  bi >>= 3;   // 8 h-tiles of 16
    const int wt = bi & 3;  bi >>= 2;   // 4 w-tiles (0:0-31,1:32-63,2:64-89,3:90-121)
    const int dc = bi;                  // 8 d-chunks

    const int h0 = ht << 4;
    const int w0 = (wt == 3) ? 90 : (wt << 5);
    const int w_hi = (wt == 3) ? 122 : ((wt == 2) ? 90 : (w0 + 32));
    const int csize = (dc < 2) ? 16 : 15;
    const int d0 = (dc < 2) ? (dc << 4) : (32 + (dc - 2) * 15);
    const int nsl = csize + 6;          // input slices: d0 .. d0+nsl-1 (<=127)

    const float dr = DR[bb];
    const float c1 = (0.01f * dr) * (0.01f * dr);
    const float c2 = (0.03f * dr) * (0.03f * dr);
    const float inv_n = 1.0f / 343.0f;
    const float covn = 343.0f / 342.0f;

    // phase A mapping
    const int sA  = tid & 15;
    const int rA0 = tid >> 4;           // rows 0..15
    const int rA1 = 16 + (tid >> 4);    // rows 16..21 (tid < 96)
    int grA0 = h0 + rA0; if (grA0 > NFULL - 1) grA0 = NFULL - 1;
    int grA1 = h0 + rA1; if (grA1 > NFULL - 1) grA1 = NFULL - 1;
    const int coffA = w0 + 2 * sA;

    // phase C mapping
    const int sC = tid & 15, hC = tid >> 4;
    const int gh  = h0 + hC;
    const int gw0 = w0 + 2 * sC;
    const bool vh = (gh < NOUT);
    const bool vld0 = vh && (gw0 < w_hi);
    const bool vld1 = vh && (gw0 + 1 < w_hi);

    const size_t planeStride = (size_t)NFULL * NFULL;
    const size_t bbase = (size_t)bb * NFULL * planeStride;

    float2 ring[7][5];
    float2 run[5];
#pragma unroll
    for (int k = 0; k < 7; ++k)
#pragma unroll
        for (int q = 0; q < 5; ++q) ring[k][q] = make_float2(0.f, 0.f);
#pragma unroll
    for (int q = 0; q < 5; ++q) run[q] = make_float2(0.f, 0.f);
    float acc = 0.0f;

    for (int base = 0; base <= nsl; base += 7) {
#pragma unroll
        for (int u = 0; u < 7; ++u) {
            const int s = base + u;     // uniform
            if (s <= nsl) {
                // ---------- phase 1: A(s) (global -> s1) || C(s-1) (s2 -> ring/SSIM)
                if (s < nsl) {
                    const int dIn = d0 + s;
                    const float* Xp = X + bbase + (size_t)dIn * planeStride;
                    const float* Yp = Y + bbase + (size_t)dIn * planeStride;
                    phaseA_task(Xp + grA0 * NFULL + coffA, Yp + grA0 * NFULL + coffA,
                                s1 + rA0 * S1_R + 2 * sA);
                    if (tid < 96)
                        phaseA_task(Xp + grA1 * NFULL + coffA, Yp + grA1 * NFULL + coffA,
                                    s1 + rA1 * S1_R + 2 * sA);
                }
                if (s >= 1) {
                    const int slot = (u + 6) % 7;   // (s-1)%7, static after unroll
                    float2 p[5];
#pragma unroll
                    for (int q = 0; q < 5; ++q)
                        p[q] = *(const float2*)(s2 + q * S2_Q + hC * S2_R + 2 * sC);
#pragma unroll
                    for (int q = 0; q < 5; ++q) {
                        run[q].x += p[q].x - ring[slot][q].x;
                        run[q].y += p[q].y - ring[slot][q].y;
                        ring[slot][q] = p[q];
                    }
                    if (s >= 7) {
#pragma unroll
                        for (int j = 0; j < 2; ++j) {
                            const bool vld = j ? vld1 : vld0;
                            if (vld) {
                                float ux  = (j ? run[0].y : run[0].x) * inv_n;
                                float uy  = (j ? run[1].y : run[1].x) * inv_n;
                                float uxx = (j ? run[2].y : run[2].x) * inv_n;
                                float uyy = (j ? run[3].y : run[3].x) * inv_n;
                                float uxy = (j ? run[4].y : run[4].x) * inv_n;
                                float vx  = covn * (uxx - ux * ux);
                                float vy  = covn * (uyy - uy * uy);
                                float vxy = covn * (uxy - ux * uy);
                                float A1  = 2.f * ux * uy + c1;
                                float A2  = 2.f * vxy + c2;
                                float B1v = ux * ux + uy * uy + c1;
                                float B2v = vx + vy + c2;
                                acc += (A1 * A2) / (B1v * B2v);
                            }
                        }
                    }
                }
                __syncthreads();
                // ---------- phase 2: B(s) (s1 -> s2), 320 4-row rolling tasks
                if (s < nsl) {
#pragma unroll
                    for (int rep = 0; rep < 2; ++rep) {
                        const int t = rep ? (256 + tid) : tid;
                        if (rep == 0 || tid < 64) {
                            const int sB  = t & 15;
                            const int tq  = t >> 4;
                            const int qB  = tq % 5;
                            const int seg = tq / 5;       // 0..3
                            const int r0  = seg << 2;
                            const float* src = s1 + qB * S1_Q + 2 * sB;
                            float*       dst = s2 + qB * S2_Q + 2 * sB;
                            float2 v[10];
#pragma unroll
                            for (int r = 0; r < 10; ++r)
                                v[r] = *(const float2*)(src + (r0 + r) * S1_R);
                            float ax = v[0].x, ay = v[0].y;
#pragma unroll
                            for (int r = 1; r < 7; ++r) { ax += v[r].x; ay += v[r].y; }
                            *(float2*)(dst + r0 * S2_R) = make_float2(ax, ay);
#pragma unroll
                            for (int i = 1; i < 4; ++i) {
                                ax += v[6 + i].x - v[i - 1].x;
                                ay += v[6 + i].y - v[i - 1].y;
                                *(float2*)(dst + (r0 + i) * S2_R) = make_float2(ax, ay);
                            }
                        }
                    }
                }
                __syncthreads();
            }
        }
    }

    // ---- reduction: wave shuffle -> LDS -> per-block partial (double) ----
#pragma unroll
    for (int off = 32; off; off >>= 1) acc += __shfl_down(acc, off);
    if ((tid & 63) == 0) s1[tid >> 6] = acc;
    __syncthreads();
    if (tid == 0) {
        double t = (double)s1[0] + (double)s1[1] + (double)s1[2] + (double)s1[3];
        if (mode) ws[blockIdx.x] = t;
        else      atomicAdd(ws, t);
    }
}

__global__ void ssim3d_finalize(const double* __restrict__ ws, float* __restrict__ out, int mode)
{
    if (mode) {
        __shared__ double sm[4];
        const int tid = threadIdx.x;
        double t = 0.0;
        for (int i = tid; i < NBLK; i += 256) t += ws[i];
#pragma unroll
        for (int off = 32; off; off >>= 1) t += __shfl_down(t, off);
        if ((tid & 63) == 0) sm[tid >> 6] = t;
        __syncthreads();
        if (tid == 0) {
            double r = sm[0] + sm[1] + sm[2] + sm[3];
            out[0] = (float)(r * (1.0 / 7263392.0));   // 4 * 122^3
        }
    } else {
        if (threadIdx.x == 0)
            out[0] = (float)(ws[0] * (1.0 / 7263392.0));
    }
}

extern "C" void kernel_launch(void* const* d_in, const int* in_sizes, int n_in,
                              void* d_out, int out_size, void* d_ws, size_t ws_size,
                              hipStream_t stream)
{
    const float* X  = (const float*)d_in[0];
    const float* Y  = (const float*)d_in[1];
    const float* DR = (const float*)d_in[2];
    double* ws = (double*)d_ws;

    const int mode = (ws_size >= NBLK * sizeof(double)) ? 1 : 0;
    if (!mode) hipMemsetAsync(d_ws, 0, sizeof(double), stream);
    ssim3d_kernel<<<NBLK, 256, 0, stream>>>(X, Y, DR, ws, mode);
    ssim3d_finalize<<<1, 256, 0, stream>>>(ws, (float*)d_out, mode);
}

// Round 4
// 123.997 us; speedup vs baseline: 1.9819x; 1.1604x over previous
//
#include <hip/hip_runtime.h>

#define NFULL 128
#define NOUT  122

// s1: [2 bufs][5 quantities][22 rows][32 cols + 2 pad]
#define S1_R 34
#define S1_Q 748           // 22 * 34
#define S1_B 3740          // 5 * 748
#define NBLK 1024

__device__ __forceinline__ void phaseA_task(const float* __restrict__ px,
                                            const float* __restrict__ py,
                                            float* __restrict__ s1p)
{
    float xs[8], ys[8];
#pragma unroll
    for (int k = 0; k < 4; ++k) {
        float2 tx = *(const float2*)(px + 2 * k);
        float2 ty = *(const float2*)(py + 2 * k);
        xs[2 * k] = tx.x; xs[2 * k + 1] = tx.y;
        ys[2 * k] = ty.x; ys[2 * k + 1] = ty.y;
    }
    float sx = 0.f, sy = 0.f, sxx = 0.f, syy = 0.f, sxy = 0.f;
#pragma unroll
    for (int k = 0; k < 7; ++k) {
        sx += xs[k]; sy += ys[k];
        sxx = fmaf(xs[k], xs[k], sxx);
        syy = fmaf(ys[k], ys[k], syy);
        sxy = fmaf(xs[k], ys[k], sxy);
    }
    float tx2 = sx - xs[0] + xs[7];
    float ty2 = sy - ys[0] + ys[7];
    float txx = sxx - xs[0] * xs[0] + xs[7] * xs[7];
    float tyy = syy - ys[0] * ys[0] + ys[7] * ys[7];
    float txy = sxy - xs[0] * ys[0] + xs[7] * ys[7];
    *(float2*)(s1p + 0 * S1_Q) = make_float2(sx,  tx2);
    *(float2*)(s1p + 1 * S1_Q) = make_float2(sy,  ty2);
    *(float2*)(s1p + 2 * S1_Q) = make_float2(sxx, txx);
    *(float2*)(s1p + 3 * S1_Q) = make_float2(syy, tyy);
    *(float2*)(s1p + 4 * S1_Q) = make_float2(sxy, txy);
}

__global__ __launch_bounds__(256, 4)
void ssim3d_kernel(const float* __restrict__ X, const float* __restrict__ Y,
                   const float* __restrict__ DR, double* __restrict__ ws, int mode)
{
    __shared__ __align__(16) float s1[2 * S1_B];   // 29920 B

    const int tid = threadIdx.x;
    int bi = blockIdx.x;
    const int bb = bi & 3;  bi >>= 2;   // batch
    const int ht = bi & 7;  bi >>= 3;   // 8 h-tiles of 16
    const int wt = bi & 3;  bi >>= 2;   // 4 w-tiles (0:0-31,1:32-63,2:64-89,3:90-121)
    const int dc = bi;                  // 8 d-chunks

    const int h0 = ht << 4;
    const int w0 = (wt == 3) ? 90 : (wt << 5);
    const int w_hi = (wt == 3) ? 122 : ((wt == 2) ? 90 : (w0 + 32));
    const int csize = (dc < 2) ? 16 : 15;
    const int d0 = (dc < 2) ? (dc << 4) : (32 + (dc - 2) * 15);
    const int nsl = csize + 6;          // input slices d0 .. d0+nsl-1 (<=127)

    // SSIM constants, scaled by 343^2 (ratio-invariant)
    const float dr = DR[bb];
    const float c1s = (0.01f * dr) * (0.01f * dr) * 117649.0f;
    const float c2s = (0.03f * dr) * (0.03f * dr) * 117649.0f;
    const float tni = 1.0f / 343.0f;
    const float kkA = 2.0f * 117649.0f / 342.0f;   // A2 coeff
    const float kkB = 117649.0f / 342.0f;          // B2 coeff

    // phase A mapping
    const int sA  = tid & 15;
    const int rA0 = tid >> 4;           // rows 0..15
    const int rA1 = 16 + (tid >> 4);    // rows 16..21 (tid < 96)
    int grA0 = h0 + rA0; if (grA0 > NFULL - 1) grA0 = NFULL - 1;
    int grA1 = h0 + rA1; if (grA1 > NFULL - 1) grA1 = NFULL - 1;
    const int coffA = w0 + 2 * sA;

    // phase C mapping
    const int sC = tid & 15, hC = tid >> 4;
    const int gh  = h0 + hC;
    const int gw0 = w0 + 2 * sC;
    const bool vh = (gh < NOUT);
    const bool vld0 = vh && (gw0 < w_hi);
    const bool vld1 = vh && (gw0 + 1 < w_hi);

    const size_t planeStride = (size_t)NFULL * NFULL;
    const size_t bbase = (size_t)bb * NFULL * planeStride;

    float2 ring[7][5];
    float2 run[5];
#pragma unroll
    for (int k = 0; k < 7; ++k)
#pragma unroll
        for (int q = 0; q < 5; ++q) ring[k][q] = make_float2(0.f, 0.f);
#pragma unroll
    for (int q = 0; q < 5; ++q) run[q] = make_float2(0.f, 0.f);
    float acc = 0.0f;

    for (int base = 0; base <= nsl; base += 7) {
#pragma unroll
        for (int u = 0; u < 7; ++u) {
            const int s = base + u;     // uniform across block
            if (s <= nsl) {
                // ---- A(s): global -> s1[s&1]  ||  C'(s-1): s1[(s-1)&1] -> ring/SSIM
                if (s < nsl) {
                    float* dst = s1 + (size_t)((s & 1) * S1_B);
                    const int dIn = d0 + s;
                    const float* Xp = X + bbase + (size_t)dIn * planeStride;
                    const float* Yp = Y + bbase + (size_t)dIn * planeStride;
                    phaseA_task(Xp + grA0 * NFULL + coffA, Yp + grA0 * NFULL + coffA,
                                dst + rA0 * S1_R + 2 * sA);
                    if (tid < 96)
                        phaseA_task(Xp + grA1 * NFULL + coffA, Yp + grA1 * NFULL + coffA,
                                    dst + rA1 * S1_R + 2 * sA);
                }
                if (s >= 1) {
                    const float* src = s1 + (size_t)(((s - 1) & 1) * S1_B)
                                          + hC * S1_R + 2 * sC;
                    const int slot = (u + 6) % 7;   // (s-1)%7, static after unroll
#pragma unroll
                    for (int q = 0; q < 5; ++q) {
                        const float* p = src + q * S1_Q;
                        float2 h = *(const float2*)p;
#pragma unroll
                        for (int r = 1; r < 7; ++r) {
                            float2 v = *(const float2*)(p + r * S1_R);
                            h.x += v.x; h.y += v.y;
                        }
                        run[q].x += h.x - ring[slot][q].x;
                        run[q].y += h.y - ring[slot][q].y;
                        ring[slot][q] = h;
                    }
                    if (s >= 7) {
#pragma unroll
                        for (int j = 0; j < 2; ++j) {
                            const bool vld = j ? vld1 : vld0;
                            if (vld) {
                                float Sx  = j ? run[0].y : run[0].x;
                                float Sy  = j ? run[1].y : run[1].x;
                                float Sxx = j ? run[2].y : run[2].x;
                                float Syy = j ? run[3].y : run[3].x;
                                float Sxy = j ? run[4].y : run[4].x;
                                float P = Sx * Sy;
                                float Q = fmaf(Sx, Sx, Sy * Sy);
                                float A1 = fmaf(2.f, P, c1s);
                                float A2 = fmaf(kkA, fmaf(-tni, P, Sxy), c2s);
                                float B1 = Q + c1s;
                                float B2 = fmaf(kkB, fmaf(-tni, Q, Sxx + Syy), c2s);
                                float num = A1 * A2;
                                float den = B1 * B2;
                                float r0 = __builtin_amdgcn_rcpf(den);
                                r0 = r0 * fmaf(-den, r0, 2.0f);   // 1 Newton step
                                acc = fmaf(num, r0, acc);
                            }
                        }
                    }
                }
                __syncthreads();
            }
        }
    }

    // ---- reduction: wave shuffle -> LDS -> per-block partial (double) ----
#pragma unroll
    for (int off = 32; off; off >>= 1) acc += __shfl_down(acc, off);
    if ((tid & 63) == 0) s1[tid >> 6] = acc;
    __syncthreads();
    if (tid == 0) {
        double t = (double)s1[0] + (double)s1[1] + (double)s1[2] + (double)s1[3];
        if (mode) ws[blockIdx.x] = t;
        else      atomicAdd(ws, t);
    }
}

__global__ void ssim3d_finalize(const double* __restrict__ ws, float* __restrict__ out, int mode)
{
    if (mode) {
        __shared__ double sm[4];
        const int tid = threadIdx.x;
        double t = 0.0;
        for (int i = tid; i < NBLK; i += 256) t += ws[i];
#pragma unroll
        for (int off = 32; off; off >>= 1) t += __shfl_down(t, off);
        if ((tid & 63) == 0) sm[tid >> 6] = t;
        __syncthreads();
        if (tid == 0) {
            double r = sm[0] + sm[1] + sm[2] + sm[3];
            out[0] = (float)(r * (1.0 / 7263392.0));   // 4 * 122^3
        }
    } else {
        if (threadIdx.x == 0)
            out[0] = (float)(ws[0] * (1.0 / 7263392.0));
    }
}

extern "C" void kernel_launch(void* const* d_in, const int* in_sizes, int n_in,
                              void* d_out, int out_size, void* d_ws, size_t ws_size,
                              hipStream_t stream)
{
    const float* X  = (const float*)d_in[0];
    const float* Y  = (const float*)d_in[1];
    const float* DR = (const float*)d_in[2];
    double* ws = (double*)d_ws;

    const int mode = (ws_size >= NBLK * sizeof(double)) ? 1 : 0;
    if (!mode) hipMemsetAsync(d_ws, 0, sizeof(double), stream);
    ssim3d_kernel<<<NBLK, 256, 0, stream>>>(X, Y, DR, ws, mode);
    ssim3d_finalize<<<1, 256, 0, stream>>>(ws, (float*)d_out, mode);
}